// Round 20
// baseline (385.737 us; speedup 1.0000x reference)
//
#include <hip/hip_runtime.h>
#include <hip/hip_bf16.h>
#include <stdint.h>

typedef int i32x4 __attribute__((ext_vector_type(4)));

constexpr int IN_F = 1024;
constexpr int OUT_F = 1024;
constexpr int M_TOT = 8 * 4096;   // 32768 tokens
constexpr int K_TOT = 1024;
constexpr int N_TOT = 1024;

// ---------------- kernel 1: per-token int8 fake-quant (+ fused weight unpack) ----------------
__global__ __launch_bounds__(256) void quant_kernel(
    const float* __restrict__ x,
    const float* __restrict__ wscale,
    const int* __restrict__ packed,
    int8_t* __restrict__ q,            // [M_TOT][K_TOT] int8
    float* __restrict__ inv_row,       // [M_TOT]
    int8_t* __restrict__ wt)           // [OUT_F][IN_F] ternary int8 (B^T)
{
    const int row = blockIdx.x;
    const int t = threadIdx.x;
    const float4 v = reinterpret_cast<const float4*>(x + (size_t)row * IN_F)[t];
    float m = fmaxf(fmaxf(fabsf(v.x), fabsf(v.y)), fmaxf(fabsf(v.z), fabsf(v.w)));
    #pragma unroll
    for (int off = 32; off > 0; off >>= 1)
        m = fmaxf(m, __shfl_xor(m, off));
    __shared__ float smax[4];
    if ((t & 63) == 0) smax[t >> 6] = m;
    __syncthreads();
    m = fmaxf(fmaxf(smax[0], smax[1]), fmaxf(smax[2], smax[3]));
    const float a = fmaxf(m, 1e-5f);
    const float as = 127.0f / a;

    char4 o;
    o.x = (char)(int)fminf(fmaxf(rintf(v.x * as), -128.0f), 127.0f);
    o.y = (char)(int)fminf(fmaxf(rintf(v.y * as), -128.0f), 127.0f);
    o.z = (char)(int)fminf(fmaxf(rintf(v.z * as), -128.0f), 127.0f);
    o.w = (char)(int)fminf(fmaxf(rintf(v.w * as), -128.0f), 127.0f);
    reinterpret_cast<char4*>(q + (size_t)row * IN_F)[t] = o;
    if (t == 0) inv_row[row] = (a / 127.0f) * wscale[0];

    // fused unpack: blocks 0..1023 also expand one weight row (r5-verified mapping)
    if (row < OUT_F) {
        const int oo = row;
        const int k0 = t * 4;
        const int sh = (oo >> 8) * 2;
        const int pbase = ((oo & 255) << 10) + k0;
        const int4 pw = *reinterpret_cast<const int4*>(packed + pbase);
        char4 r;
        r.x = (char)(((pw.x >> sh) & 3) - 1);
        r.y = (char)(((pw.y >> sh) & 3) - 1);
        r.z = (char)(((pw.z >> sh) & 3) - 1);
        r.w = (char)(((pw.w >> sh) & 3) - 1);
        *reinterpret_cast<char4*>(wt + (size_t)oo * IN_F + k0) = r;
    }
}

// ---------------- kernel 2: int8 MFMA GEMM, r16 schedule @ BK=64, 2 blocks/CU ----------------
// 256x256 tile, BK=64 (NT=16), 8 waves (2M x 4N), 128x64/wave.
// LDS = 2buf x (A 16KB + B 16KB) = 64 KiB -> TWO blocks co-resident per CU
// (grid 512 = all resident, one round): sibling block's MFMA bursts fill this
// block's barrier/staging/write stalls. Regs: 128 arch + 128 acc = 256/wave,
// 4 waves/SIMD x 256 = 1024 <= 2048 pool.
// lgkm pipeline (r13/r16-proven): entering tile T, Ph0 frags (aF4+bF4) in flight;
// issue aG (4) + stage T+1 (4 vm) -> lgkmcnt(4) certifies Ph0 -> 16 MFMA ->
// lgkmcnt(0) certifies aG -> 16 MFMA -> vmcnt(0) -> barrier -> pre-read Ph0(T+1).
// Swizzle (BK=64, 4 chunks/row): ch ^= (local>>1)&3 involution, linear LDS dest,
// inverse-swizzled global src (j-invariant) -- r8-measured 0 conflicts.
constexpr int BM = 256, BN = 256, BK = 64;
constexpr int NT = K_TOT / BK;   // 16

__global__ __launch_bounds__(512, 4) void gemm_kernel(
    const int8_t* __restrict__ qa,     // [M_TOT][K_TOT] int8
    const int8_t* __restrict__ wb,     // [N_TOT][K_TOT] int8
    const float* __restrict__ inv_row,
    const float* __restrict__ bias,
    float* __restrict__ out)
{
    // XCD-aware swizzle: nwg = 512, divisible by 8 -> bijective simple remap
    int bid = blockIdx.x;
    bid = (bid & 7) * ((int)gridDim.x >> 3) + (bid >> 3);
    const int tm = bid >> 2;            // 0..127
    const int tn = bid & 3;             // 0..3

    const int tid = threadIdx.x;
    const int lane = tid & 63;
    const int wid = tid >> 6;           // 0..7
    const int wr = wid >> 2;            // 0..1 (M half: rows wr*128..)
    const int wc = wid & 3;             // 0..3 (N quarter: cols wc*64..)

    __shared__ int8_t lds[2][2][256 * 64];   // [buf][ab] 16 KiB each = 64 KiB

    const int rowA0 = tm * BM;
    const int rowB0 = tn * BN;
    const int frow = lane & 15;
    const int fq = lane >> 4;

    i32x4 acc[8][4] = {};

    // staging: chunk c = j*512 + tid (16B); rl = c>>2 (0..255), cc = c&3;
    // source chunk scc = cc ^ ((rl>>1)&3) -- j-invariant (j adds 128 to rl; 64&3==0).
    const int rl0 = tid >> 2;
    const int scc0 = (tid & 3) ^ ((rl0 >> 1) & 3);

    auto stage = [&](int buf, int ab, int kt) {
        const int8_t* base = ab ? wb : qa;
        const int row0 = ab ? rowB0 : rowA0;
        #pragma unroll
        for (int j = 0; j < 2; ++j) {
            const int8_t* src = base + (size_t)(row0 + rl0 + j * 128) * K_TOT
                                     + kt * BK + scc0 * 16;
            __builtin_amdgcn_global_load_lds(
                (const __attribute__((address_space(1))) void*)src,
                (__attribute__((address_space(3))) void*)&lds[buf][ab][(j * 512 + tid) * 16],
                16, 0, 0);
        }
    };

    auto ldA = [&](int buf, int half, int mf) -> i32x4 {
        const int local = wr * 128 + half * 64 + mf * 16 + frow;
        const int ch = fq ^ ((local >> 1) & 3);
        return *reinterpret_cast<const i32x4*>(&lds[buf][0][local * 64 + ch * 16]);
    };
    auto ldB = [&](int buf, int nf) -> i32x4 {
        const int local = wc * 64 + nf * 16 + frow;
        const int ch = fq ^ ((local >> 1) & 3);
        return *reinterpret_cast<const i32x4*>(&lds[buf][1][local * 64 + ch * 16]);
    };

    i32x4 aF[4], bF[4], aG[4];

    // prologue: stage tile0 (4 loads), certify, barrier, pre-read Ph0(0)
    stage(0, 1, 0); stage(0, 0, 0);
    asm volatile("s_waitcnt vmcnt(0)" ::: "memory");
    __builtin_amdgcn_s_barrier();
    #pragma unroll
    for (int mf = 0; mf < 4; ++mf) aF[mf] = ldA(0, 0, mf);
    #pragma unroll
    for (int nf = 0; nf < 4; ++nf) bF[nf] = ldB(0, nf);
    // 8 ds_reads outstanding entering the loop

    #pragma unroll 1
    for (int T = 0; T < NT; ++T) {
        const int cur = T & 1, nxt = cur ^ 1;
        const bool st = (T + 1 < NT);

        // issue Ph1 reads (rows-hi -> aG) and tile T+1's staging
        #pragma unroll
        for (int mf = 0; mf < 4; ++mf) aG[mf] = ldA(cur, 1, mf);
        if (st) { stage(nxt, 1, T + 1); stage(nxt, 0, T + 1); }

        asm volatile("s_waitcnt lgkmcnt(4)" ::: "memory");   // Ph0 frags certified
        __builtin_amdgcn_sched_barrier(0);
        __builtin_amdgcn_s_setprio(1);
        #pragma unroll
        for (int mf = 0; mf < 4; ++mf)
            #pragma unroll
            for (int nf = 0; nf < 4; ++nf)
                acc[mf][nf] = __builtin_amdgcn_mfma_i32_16x16x64_i8(
                    aF[mf], bF[nf], acc[mf][nf], 0, 0, 0);
        __builtin_amdgcn_s_setprio(0);

        asm volatile("s_waitcnt lgkmcnt(0)" ::: "memory");   // Ph1 frags (hidden under Ph0)
        __builtin_amdgcn_sched_barrier(0);
        __builtin_amdgcn_s_setprio(1);
        #pragma unroll
        for (int mf = 0; mf < 4; ++mf)
            #pragma unroll
            for (int nf = 0; nf < 4; ++nf)
                acc[4 + mf][nf] = __builtin_amdgcn_mfma_i32_16x16x64_i8(
                    aG[mf], bF[nf], acc[4 + mf][nf], 0, 0, 0);
        __builtin_amdgcn_s_setprio(0);

        if (st) {
            asm volatile("s_waitcnt vmcnt(0)" ::: "memory"); // my T+1 stages landed
            __builtin_amdgcn_s_barrier();                    // everyone's landed; T-reads done
            // pre-read Ph0(T+1): rows-lo + B
            #pragma unroll
            for (int mf = 0; mf < 4; ++mf) aF[mf] = ldA(nxt, 0, mf);
            #pragma unroll
            for (int nf = 0; nf < 4; ++nf) bF[nf] = ldB(nxt, nf);
        }
    }

    // epilogue: C/D 16x16 layout (col = lane&15, row = fq*4 + reg); plain stores
    // (r16: nontemporal caused 131->185MB write amplification).
    #pragma unroll
    for (int mi = 0; mi < 8; ++mi) {
        #pragma unroll
        for (int j = 0; j < 4; ++j) {
            const int gm = rowA0 + wr * 128 + mi * 16 + fq * 4 + j;
            const float sc = inv_row[gm];
            #pragma unroll
            for (int nf = 0; nf < 4; ++nf) {
                const int gn = rowB0 + wc * 64 + nf * 16 + frow;
                out[(size_t)gm * N_TOT + gn] = (float)acc[mi][nf][j] * sc + bias[gn];
            }
        }
    }
}

extern "C" void kernel_launch(void* const* d_in, const int* in_sizes, int n_in,
                              void* d_out, int out_size, void* d_ws, size_t ws_size,
                              hipStream_t stream) {
    const float* x = (const float*)d_in[0];
    const int* packed = (const int*)d_in[1];
    const float* wscale = (const float*)d_in[2];
    const float* bias = (const float*)d_in[3];
    float* out = (float*)d_out;

    int8_t* q = (int8_t*)d_ws;                                          // 32 MiB
    int8_t* wt = (int8_t*)((char*)d_ws + (size_t)M_TOT * K_TOT);        // 1 MiB
    float* inv_row = (float*)((char*)d_ws + (size_t)M_TOT * K_TOT + (size_t)N_TOT * K_TOT);

    quant_kernel<<<M_TOT, 256, 0, stream>>>(x, wscale, packed, q, inv_row, wt);
    gemm_kernel<<<(M_TOT / BM) * (N_TOT / BN), 512, 0, stream>>>(q, wt, inv_row, bias, out);
}

// Round 21
// 84.702 us; speedup vs baseline: 4.5540x; 4.5540x over previous
//
#include <hip/hip_runtime.h>
#include <hip/hip_bf16.h>
#include <stdint.h>

typedef int i32x4 __attribute__((ext_vector_type(4)));

constexpr int IN_F = 1024;
constexpr int OUT_F = 1024;
constexpr int M_TOT = 8 * 4096;   // 32768 tokens
constexpr int K_TOT = 1024;
constexpr int N_TOT = 1024;

// ---------------- kernel 1: per-token int8 fake-quant (+ fused weight unpack) ----------------
__global__ __launch_bounds__(256) void quant_kernel(
    const float* __restrict__ x,
    const float* __restrict__ wscale,
    const int* __restrict__ packed,
    int8_t* __restrict__ q,            // [M_TOT][K_TOT] int8
    float* __restrict__ inv_row,       // [M_TOT]
    int8_t* __restrict__ wt)           // [OUT_F][IN_F] ternary int8 (B^T)
{
    const int row = blockIdx.x;
    const int t = threadIdx.x;
    const float4 v = reinterpret_cast<const float4*>(x + (size_t)row * IN_F)[t];
    float m = fmaxf(fmaxf(fabsf(v.x), fabsf(v.y)), fmaxf(fabsf(v.z), fabsf(v.w)));
    #pragma unroll
    for (int off = 32; off > 0; off >>= 1)
        m = fmaxf(m, __shfl_xor(m, off));
    __shared__ float smax[4];
    if ((t & 63) == 0) smax[t >> 6] = m;
    __syncthreads();
    m = fmaxf(fmaxf(smax[0], smax[1]), fmaxf(smax[2], smax[3]));
    const float a = fmaxf(m, 1e-5f);
    const float as = 127.0f / a;

    char4 o;
    o.x = (char)(int)fminf(fmaxf(rintf(v.x * as), -128.0f), 127.0f);
    o.y = (char)(int)fminf(fmaxf(rintf(v.y * as), -128.0f), 127.0f);
    o.z = (char)(int)fminf(fmaxf(rintf(v.z * as), -128.0f), 127.0f);
    o.w = (char)(int)fminf(fmaxf(rintf(v.w * as), -128.0f), 127.0f);
    reinterpret_cast<char4*>(q + (size_t)row * IN_F)[t] = o;
    if (t == 0) inv_row[row] = (a / 127.0f) * wscale[0];

    // fused unpack: blocks 0..1023 also expand one weight row (r5-verified mapping)
    if (row < OUT_F) {
        const int oo = row;
        const int k0 = t * 4;
        const int sh = (oo >> 8) * 2;
        const int pbase = ((oo & 255) << 10) + k0;
        const int4 pw = *reinterpret_cast<const int4*>(packed + pbase);
        char4 r;
        r.x = (char)(((pw.x >> sh) & 3) - 1);
        r.y = (char)(((pw.y >> sh) & 3) - 1);
        r.z = (char)(((pw.z >> sh) & 3) - 1);
        r.w = (char)(((pw.w >> sh) & 3) - 1);
        *reinterpret_cast<char4*>(wt + (size_t)oo * IN_F + k0) = r;
    }
}

// ---------------- kernel 2: int8 MFMA GEMM, r16 champion (restored) ----------------
// 256x256, BK=128, 8 waves (2M x 4N), 128x64/wave, dbuf, involution swizzle
// (0-conflict), lgkm-pipelined frag reads, plain C stores (nontemporal caused
// 131->185MB write amplification). 1 block/CU, 2 rounds; round-2 blocks overlap
// round-1's C-store drain (endpgm frees the slot with stores in flight).
// Steady-state: Ph0 frags (16 ds_read) in flight entering tile T; issue Ph1 reads
// (8) + stage T+1 (8 vm) -> lgkmcnt(8) certifies Ph0 -> 32 MFMA -> lgkmcnt(0)
// certifies Ph1 (hidden under Ph0 burst) -> 32 MFMA -> vmcnt(0) -> barrier ->
// pre-read Ph0(T+1). Registers: 128 arch + 128 acc = 256/wave, 2 waves/SIMD (max).
constexpr int BM = 256, BN = 256, BK = 128;
constexpr int NT = K_TOT / BK;   // 8

__global__ __launch_bounds__(512, 2) void gemm_kernel(
    const int8_t* __restrict__ qa,     // [M_TOT][K_TOT] int8
    const int8_t* __restrict__ wb,     // [N_TOT][K_TOT] int8
    const float* __restrict__ inv_row,
    const float* __restrict__ bias,
    float* __restrict__ out)
{
    // XCD-aware swizzle: nwg = 512, divisible by 8 -> bijective simple remap
    int bid = blockIdx.x;
    bid = (bid & 7) * ((int)gridDim.x >> 3) + (bid >> 3);
    const int tm = bid >> 2;            // 0..127
    const int tn = bid & 3;             // 0..3

    const int tid = threadIdx.x;
    const int lane = tid & 63;
    const int wid = tid >> 6;           // 0..7
    const int wr = wid >> 2;            // 0..1 (M half)
    const int wc = wid & 3;             // 0..3 (N quarter)

    __shared__ int8_t lds[2][2][2][128 * 128];  // [buf][ab][region] = 128 KiB

    const int rowA0 = tm * BM;
    const int rowB0 = tn * BN;
    const int frow = lane & 15;
    const int fq = lane >> 4;

    i32x4 acc[8][4] = {};

    auto stage = [&](int buf, int ab, int region, int kt) {
        const int8_t* base = ab ? wb : qa;
        #pragma unroll
        for (int j = 0; j < 2; ++j) {
            const int c = j * 512 + tid;
            const int rl = c >> 3, cc = c & 7;
            const int grow = ab ? (rowB0 + region * 128 + rl)
                                : (rowA0 + (rl & 64) * 2 + region * 64 + (rl & 63));
            const int scc = cc ^ (rl & 7);
            const int8_t* src = base + (size_t)grow * K_TOT + kt * BK + scc * 16;
            __builtin_amdgcn_global_load_lds(
                (const __attribute__((address_space(1))) void*)src,
                (__attribute__((address_space(3))) void*)&lds[buf][ab][region][c * 16],
                16, 0, 0);
        }
    };

    auto ldA = [&](int buf, int region, int mf, int ks) -> i32x4 {
        const int local = wr * 64 + (mf & 3) * 16 + frow;
        const int ch = (ks * 4 + fq) ^ (local & 7);
        return *reinterpret_cast<const i32x4*>(&lds[buf][0][region][local * 128 + ch * 16]);
    };
    auto ldB = [&](int buf, int nf, int ks) -> i32x4 {
        const int region = wc >> 1;
        const int local = (wc & 1) * 64 + nf * 16 + frow;
        const int ch = (ks * 4 + fq) ^ (local & 7);
        return *reinterpret_cast<const i32x4*>(&lds[buf][1][region][local * 128 + ch * 16]);
    };

    i32x4 aF[4][2], bF[4][2], aG[4][2];

    // prologue: stage tile0 (B then A), certify, barrier, pre-read Ph0(0)
    stage(0, 1, 0, 0); stage(0, 1, 1, 0); stage(0, 0, 0, 0); stage(0, 0, 1, 0);
    asm volatile("s_waitcnt vmcnt(0)" ::: "memory");
    __builtin_amdgcn_s_barrier();
    #pragma unroll
    for (int mf = 0; mf < 4; ++mf)
        #pragma unroll
        for (int ks = 0; ks < 2; ++ks)
            aF[mf][ks] = ldA(0, 0, mf, ks);
    #pragma unroll
    for (int nf = 0; nf < 4; ++nf)
        #pragma unroll
        for (int ks = 0; ks < 2; ++ks)
            bF[nf][ks] = ldB(0, nf, ks);
    // 16 ds_reads outstanding entering the loop

    #pragma unroll 1
    for (int T = 0; T < NT; ++T) {
        const int cur = T & 1, nxt = cur ^ 1;
        const bool st = (T + 1 < NT);

        // issue Ph1 reads (A-R1 -> aG) and all of tile T+1's staging
        #pragma unroll
        for (int mf = 0; mf < 4; ++mf)
            #pragma unroll
            for (int ks = 0; ks < 2; ++ks)
                aG[mf][ks] = ldA(cur, 1, mf, ks);
        if (st) {
            stage(nxt, 1, 0, T + 1); stage(nxt, 1, 1, T + 1);
            stage(nxt, 0, 0, T + 1); stage(nxt, 0, 1, T + 1);
        }

        asm volatile("s_waitcnt lgkmcnt(8)" ::: "memory");   // Ph0 frags certified
        __builtin_amdgcn_sched_barrier(0);
        __builtin_amdgcn_s_setprio(1);
        #pragma unroll
        for (int mf = 0; mf < 4; ++mf)
            #pragma unroll
            for (int nf = 0; nf < 4; ++nf)
                #pragma unroll
                for (int ks = 0; ks < 2; ++ks)
                    acc[mf][nf] = __builtin_amdgcn_mfma_i32_16x16x64_i8(
                        aF[mf][ks], bF[nf][ks], acc[mf][nf], 0, 0, 0);
        __builtin_amdgcn_s_setprio(0);

        asm volatile("s_waitcnt lgkmcnt(0)" ::: "memory");   // Ph1 frags (hidden under Ph0)
        __builtin_amdgcn_sched_barrier(0);
        __builtin_amdgcn_s_setprio(1);
        #pragma unroll
        for (int mf = 0; mf < 4; ++mf)
            #pragma unroll
            for (int nf = 0; nf < 4; ++nf)
                #pragma unroll
                for (int ks = 0; ks < 2; ++ks)
                    acc[4 + mf][nf] = __builtin_amdgcn_mfma_i32_16x16x64_i8(
                        aG[mf][ks], bF[nf][ks], acc[4 + mf][nf], 0, 0, 0);
        __builtin_amdgcn_s_setprio(0);

        if (st) {
            asm volatile("s_waitcnt vmcnt(0)" ::: "memory"); // my T+1 stages landed
            __builtin_amdgcn_s_barrier();                    // everyone's landed; T-reads done
            // pre-read Ph0(T+1): A-R0 + B
            #pragma unroll
            for (int mf = 0; mf < 4; ++mf)
                #pragma unroll
                for (int ks = 0; ks < 2; ++ks)
                    aF[mf][ks] = ldA(nxt, 0, mf, ks);
            #pragma unroll
            for (int nf = 0; nf < 4; ++nf)
                #pragma unroll
                for (int ks = 0; ks < 2; ++ks)
                    bF[nf][ks] = ldB(nxt, nf, ks);
        }
    }

    // epilogue: C/D 16x16 layout: col = lane&15, row = fq*4 + reg; PLAIN stores
    // (L2 merges the 4x64-B segments into 128-B lines; nontemporal defeated that).
    #pragma unroll
    for (int mi = 0; mi < 8; ++mi) {
        #pragma unroll
        for (int j = 0; j < 4; ++j) {
            const int gm = rowA0 + wr * 128 + mi * 16 + fq * 4 + j;
            const float sc = inv_row[gm];
            #pragma unroll
            for (int nf = 0; nf < 4; ++nf) {
                const int gn = rowB0 + wc * 64 + nf * 16 + frow;
                out[(size_t)gm * N_TOT + gn] = (float)acc[mi][nf][j] * sc + bias[gn];
            }
        }
    }
}

extern "C" void kernel_launch(void* const* d_in, const int* in_sizes, int n_in,
                              void* d_out, int out_size, void* d_ws, size_t ws_size,
                              hipStream_t stream) {
    const float* x = (const float*)d_in[0];
    const int* packed = (const int*)d_in[1];
    const float* wscale = (const float*)d_in[2];
    const float* bias = (const float*)d_in[3];
    float* out = (float*)d_out;

    int8_t* q = (int8_t*)d_ws;                                          // 32 MiB
    int8_t* wt = (int8_t*)((char*)d_ws + (size_t)M_TOT * K_TOT);        // 1 MiB
    float* inv_row = (float*)((char*)d_ws + (size_t)M_TOT * K_TOT + (size_t)N_TOT * K_TOT);

    quant_kernel<<<M_TOT, 256, 0, stream>>>(x, wscale, packed, q, inv_row, wt);
    gemm_kernel<<<(M_TOT / BM) * (N_TOT / BN), 512, 0, stream>>>(q, wt, inv_row, bias, out);
}